// Round 2
// baseline (4028.745 us; speedup 1.0000x reference)
//
#include <hip/hip_runtime.h>

typedef unsigned short u16;

__device__ __forceinline__ float b2f(u16 u){ return __uint_as_float(((unsigned int)u) << 16); }
__device__ __forceinline__ u16 f2b(float f){
  unsigned int x = __float_as_uint(f);
  unsigned int r = (x + 0x7FFFu + ((x >> 16) & 1u)) >> 16;
  return (u16)r;
}
__device__ __forceinline__ float4 ld4b(const u16* p){
  ushort4 u = *reinterpret_cast<const ushort4*>(p);
  return make_float4(b2f(u.x), b2f(u.y), b2f(u.z), b2f(u.w));
}
__device__ __forceinline__ void st4b(u16* p, float a, float b, float c, float d){
  ushort4 u; u.x=f2b(a); u.y=f2b(b); u.z=f2b(c); u.w=f2b(d);
  *reinterpret_cast<ushort4*>(p) = u;
}
__device__ __forceinline__ float sigm(float x){ return 1.f/(1.f+__expf(-x)); }
__device__ __forceinline__ float siluf(float x){ return x/(1.f+__expf(-x)); }
__device__ __forceinline__ float wsum(float v){
  #pragma unroll
  for (int o=1;o<64;o<<=1) v += __shfl_xor(v, o);
  return v;
}
__device__ __forceinline__ float wmax(float v){
  #pragma unroll
  for (int o=1;o<64;o<<=1) v = fmaxf(v, __shfl_xor(v, o));
  return v;
}

struct GP {
  const float* x_s; const float* x_v; const int* bidx;
  const float* wh[5]; const float* ws_w[5]; const float* ws_b[5];
  const float* wv[4]; const float* wsv_w[4]; const float* wsv_b[4];
  const float *w1, *b1, *lng, *lnb, *w2, *b2, *gbias;
  u16 *wsT, *whT, *wvT, *wsvT, *w1T, *w2T;
  float *wsb_f, *wsvb_f, *b1_f, *b2_f, *lng_f, *lnb_f, *gb_f;
  u16 *Ks, *Vs, *Kv, *Vv, *Gs;
  float *Pm, *Gv, *CK, *CV;
  float *Qs, *Qv;   // live inside d_out (f32 scratch, overwritten with final output)
};

// ---------------- prep: weights -> [k][out] bf16, biases -> f32 copies -------
__global__ __launch_bounds__(256) void kprep(GP p){
  int idx = blockIdx.x*256 + threadIdx.x;
  if (idx < 409600){ int s=idx/81920, r=idx%81920, j=r>>8, i=r&255;
    p.wsT[idx] = f2b(p.ws_w[s][i*320 + j]); return; }
  idx -= 409600;
  if (idx < 20480){ int s=idx/4096, r=idx%4096, d=r>>6, h=r&63;
    p.whT[idx] = f2b(p.wh[s][h*64 + d]); return; }
  idx -= 20480;
  if (idx < 16384){ int s=idx/4096, r=idx%4096, h=r>>6, d=r&63;
    p.wvT[idx] = f2b(p.wv[s][d*64 + h]); return; }
  idx -= 16384;
  if (idx < 65536){ int s=idx/16384, r=idx%16384, i=r>>6, d=r&63;
    p.wsvT[idx] = f2b(p.wsv_w[s][d*256 + i]); return; }
  idx -= 65536;
  if (idx < 65536){ int j=idx>>8, i=idx&255; p.w1T[idx] = f2b(p.w1[i*256 + j]); return; }
  idx -= 65536;
  if (idx < 16384){ int i=idx>>6, r=idx&63; p.w2T[idx] = f2b(p.w2[r*256 + i]); return; }
  idx -= 16384;
  if (idx < 1280){ int s=idx>>8, i=idx&255; p.wsb_f[idx] = p.ws_b[s][i]; return; }
  idx -= 1280;
  if (idx < 256){ int s=idx>>6, d=idx&63; p.wsvb_f[idx] = p.wsv_b[s][d]; return; }
  idx -= 256;
  if (idx < 256){ p.b1_f[idx] = p.b1[idx]; return; }
  idx -= 256;
  if (idx < 64){ p.b2_f[idx] = p.b2[idx]; return; }
  idx -= 64;
  if (idx < 256){ p.lng_f[idx] = p.lng[idx]; return; }
  idx -= 256;
  if (idx < 256){ p.lnb_f[idx] = p.lnb[idx]; return; }
  idx -= 256;
  if (idx < 256){ p.gb_f[idx] = p.gbias[idx]; return; }
}

// ---------------- shared GEMM helpers (16 nodes / block, 256 threads) --------
// vh[c][h] = sum_d vt[c][d]*wh[h][d];  thread: h=lane, acc over 4 nodes (ntb..+3)
__device__ __forceinline__ void gvp_vh(const u16* W, const float* xv, float* vhb,
                                       int lane, int ntb){
  float acc[3][4];
  #pragma unroll
  for (int c=0;c<3;c++){acc[c][0]=0;acc[c][1]=0;acc[c][2]=0;acc[c][3]=0;}
  for (int d4=0; d4<64; d4+=4){
    float w0=b2f(W[(d4+0)*64+lane]);
    float w1=b2f(W[(d4+1)*64+lane]);
    float w2=b2f(W[(d4+2)*64+lane]);
    float w3=b2f(W[(d4+3)*64+lane]);
    #pragma unroll
    for (int c=0;c<3;c++){
      #pragma unroll
      for (int q=0;q<4;q++){
        float4 x = *reinterpret_cast<const float4*>(&xv[(ntb+q)*192 + c*64 + d4]);
        acc[c][q] += x.x*w0 + x.y*w1 + x.z*w2 + x.w*w3;
      }
    }
  }
  #pragma unroll
  for (int c=0;c<3;c++)
    #pragma unroll
    for (int q=0;q<4;q++)
      vhb[(ntb+q)*192 + c*64 + lane] = acc[c][q];
}

__device__ __forceinline__ void calc_vn(const float* vhb, float* vnb, int tid){
  for (int idx=tid; idx<1024; idx+=256){
    int nt=idx>>6, h=idx&63;
    float a=vhb[nt*192+h], b=vhb[nt*192+64+h], c=vhb[nt*192+128+h];
    vnb[idx] = sqrtf(fmaxf(a*a+b*b+c*c, 1e-8f));
  }
}

// s_out[i] = sum_j cat(xs,vn)[j]*W[j][i] + b[i]; thread: i=lane*4..+3, 4 nodes
template<bool HASVN>
__device__ __forceinline__ void sgemm(const u16* W, const float* bvec,
                                      const float* xs, const float* vnb,
                                      int lane, int ntb, float acc[4][4]){
  #pragma unroll
  for (int ii=0;ii<4;ii++){acc[ii][0]=0;acc[ii][1]=0;acc[ii][2]=0;acc[ii][3]=0;}
  for (int j4=0;j4<256;j4+=4){
    float4 w0 = ld4b(W + (j4+0)*256 + lane*4);
    float4 w1 = ld4b(W + (j4+1)*256 + lane*4);
    float4 w2 = ld4b(W + (j4+2)*256 + lane*4);
    float4 w3 = ld4b(W + (j4+3)*256 + lane*4);
    #pragma unroll
    for (int q=0;q<4;q++){
      float4 x = *reinterpret_cast<const float4*>(&xs[(ntb+q)*256 + j4]);
      acc[0][q] += x.x*w0.x + x.y*w1.x + x.z*w2.x + x.w*w3.x;
      acc[1][q] += x.x*w0.y + x.y*w1.y + x.z*w2.y + x.w*w3.y;
      acc[2][q] += x.x*w0.z + x.y*w1.z + x.z*w2.z + x.w*w3.z;
      acc[3][q] += x.x*w0.w + x.y*w1.w + x.z*w2.w + x.w*w3.w;
    }
  }
  if (HASVN){
    for (int h4=0;h4<64;h4+=4){
      float4 w0 = ld4b(W + (256+h4+0)*256 + lane*4);
      float4 w1 = ld4b(W + (256+h4+1)*256 + lane*4);
      float4 w2 = ld4b(W + (256+h4+2)*256 + lane*4);
      float4 w3 = ld4b(W + (256+h4+3)*256 + lane*4);
      #pragma unroll
      for (int q=0;q<4;q++){
        float4 x = *reinterpret_cast<const float4*>(&vnb[(ntb+q)*64 + h4]);
        acc[0][q] += x.x*w0.x + x.y*w1.x + x.z*w2.x + x.w*w3.x;
        acc[1][q] += x.x*w0.y + x.y*w1.y + x.z*w2.y + x.w*w3.y;
        acc[2][q] += x.x*w0.z + x.y*w1.z + x.z*w2.z + x.w*w3.z;
        acc[3][q] += x.x*w0.w + x.y*w1.w + x.z*w2.w + x.w*w3.w;
      }
    }
  }
  float4 bb = *reinterpret_cast<const float4*>(&bvec[lane*4]);
  #pragma unroll
  for (int q=0;q<4;q++){
    acc[0][q]+=bb.x; acc[1][q]+=bb.y; acc[2][q]+=bb.z; acc[3][q]+=bb.w;
  }
}

// out[q] = sum_i X[nt][i]*W[i][lane]  (K=256 -> 64 outputs)
__device__ __forceinline__ void gemm64(const u16* W, const float* X,
                                       int lane, int ntb, float out[4]){
  float a0=0,a1=0,a2=0,a3=0;
  for (int i4=0;i4<256;i4+=4){
    float w0=b2f(W[(i4+0)*64+lane]);
    float w1=b2f(W[(i4+1)*64+lane]);
    float w2=b2f(W[(i4+2)*64+lane]);
    float w3=b2f(W[(i4+3)*64+lane]);
    float4 x0 = *reinterpret_cast<const float4*>(&X[(ntb+0)*256 + i4]);
    float4 x1 = *reinterpret_cast<const float4*>(&X[(ntb+1)*256 + i4]);
    float4 x2 = *reinterpret_cast<const float4*>(&X[(ntb+2)*256 + i4]);
    float4 x3 = *reinterpret_cast<const float4*>(&X[(ntb+3)*256 + i4]);
    a0 += x0.x*w0 + x0.y*w1 + x0.z*w2 + x0.w*w3;
    a1 += x1.x*w0 + x1.y*w1 + x1.z*w2 + x1.w*w3;
    a2 += x2.x*w0 + x2.y*w1 + x2.z*w2 + x2.w*w3;
    a3 += x3.x*w0 + x3.y*w1 + x3.z*w2 + x3.w*w3;
  }
  out[0]=a0; out[1]=a1; out[2]=a2; out[3]=a3;
}

// vo[c][d=lane] = sum_h vh[c][h]*wv[d][h]
__device__ __forceinline__ void gemmWv(const u16* W, const float* vhb,
                                       int lane, int ntb, float vo[3][4]){
  #pragma unroll
  for (int c=0;c<3;c++){vo[c][0]=0;vo[c][1]=0;vo[c][2]=0;vo[c][3]=0;}
  for (int h4=0;h4<64;h4+=4){
    float w0=b2f(W[(h4+0)*64+lane]);
    float w1=b2f(W[(h4+1)*64+lane]);
    float w2=b2f(W[(h4+2)*64+lane]);
    float w3=b2f(W[(h4+3)*64+lane]);
    #pragma unroll
    for (int c=0;c<3;c++){
      #pragma unroll
      for (int q=0;q<4;q++){
        float4 x = *reinterpret_cast<const float4*>(&vhb[(ntb+q)*192 + c*64 + h4]);
        vo[c][q] += x.x*w0 + x.y*w1 + x.z*w2 + x.w*w3;
      }
    }
  }
}

// ---------------- k1: q/k/v/g GVPs + comp path (16 nodes / block) -----------
__global__ __launch_bounds__(256) void k1(GP p){
  const int tid = threadIdx.x;
  const int n0 = blockIdx.x * 16;
  __shared__ __align__(16) float xs[4096];
  __shared__ __align__(16) float xv[3072];
  __shared__ __align__(16) float vhb[3072];
  __shared__ __align__(16) float vnb[1024];
  __shared__ __align__(16) float sg[4096];

  for (int idx=tid; idx<4096; idx+=256){
    int nt=idx>>8, j=idx&255;
    xs[idx] = p.x_s[(size_t)(n0+nt)*256 + j];
  }
  for (int idx=tid; idx<3072; idx+=256){
    int nt=idx/192, k=idx-nt*192;
    int d=k/3, c=k-d*3;
    xv[nt*192 + c*64 + d] = p.x_v[(size_t)(n0+nt)*192 + k];
  }
  __syncthreads();

  const int lane = tid & 63;
  const int ng = tid >> 6;
  const int ntb = ng*4;
  float acc[4][4];

  #pragma unroll 1
  for (int s=0; s<4; ++s){            // 0=q 1=k 2=v 3=g
    gvp_vh(p.whT + s*4096, xv, vhb, lane, ntb);
    __syncthreads();
    calc_vn(vhb, vnb, tid);
    __syncthreads();
    sgemm<true>(p.wsT + (size_t)s*81920, p.wsb_f + s*256, xs, vnb, lane, ntb, acc);
    if (s < 3){
      #pragma unroll
      for (int q=0;q<4;q++){
        int n = n0 + ntb + q;
        float4 sl = make_float4(siluf(acc[0][q]), siluf(acc[1][q]),
                                siluf(acc[2][q]), siluf(acc[3][q]));
        if (s == 0)
          *reinterpret_cast<float4*>(&p.Qs[(size_t)n*256 + lane*4]) = sl;
        else {
          u16* Sd = (s==1) ? p.Ks : p.Vs;
          st4b(Sd + (size_t)n*256 + lane*4, sl.x, sl.y, sl.z, sl.w);
        }
        float4 sv = make_float4(sigm(acc[0][q]), sigm(acc[1][q]),
                                sigm(acc[2][q]), sigm(acc[3][q]));
        *reinterpret_cast<float4*>(&sg[(ntb+q)*256 + lane*4]) = sv;
      }
      __syncthreads();
      float g4[4];
      gemm64(p.wsvT + s*16384, sg, lane, ntb, g4);
      #pragma unroll
      for (int q=0;q<4;q++) g4[q] = sigm(g4[q] + p.wsvb_f[s*64 + lane]);
      float vo[3][4];
      gemmWv(p.wvT + s*4096, vhb, lane, ntb, vo);
      #pragma unroll
      for (int q=0;q<4;q++){
        int n = n0 + ntb + q;
        if (s == 0){
          #pragma unroll
          for (int c=0;c<3;c++)
            p.Qv[(size_t)n*192 + c*64 + lane] = vo[c][q]*g4[q];
        } else {
          u16* Vd = (s==1) ? p.Kv : p.Vv;
          #pragma unroll
          for (int c=0;c<3;c++)
            Vd[(size_t)n*192 + c*64 + lane] = f2b(vo[c][q]*g4[q]);
        }
      }
      __syncthreads();
    } else {
      // gate GVP: gate_s = sigmoid(s_out + gate_bias), gate_v = sigmoid(mean)
      float psum[4];
      #pragma unroll
      for (int q=0;q<4;q++){
        int n = n0 + ntb + q;
        float g0 = sigm(acc[0][q] + p.gb_f[lane*4+0]);
        float g1 = sigm(acc[1][q] + p.gb_f[lane*4+1]);
        float g2 = sigm(acc[2][q] + p.gb_f[lane*4+2]);
        float g3 = sigm(acc[3][q] + p.gb_f[lane*4+3]);
        st4b(p.Gs + (size_t)n*256 + lane*4, g0,g1,g2,g3);
        psum[q] = g0+g1+g2+g3;
      }
      #pragma unroll
      for (int q=0;q<4;q++) psum[q] = wsum(psum[q]);
      if (lane==0){
        #pragma unroll
        for (int q=0;q<4;q++) p.Gv[n0+ntb+q] = sigm(psum[q]*(1.f/256.f));
      }
      __syncthreads();
    }
  }

  // comp path: h = LN(xs @ w1.T + b1); P = softmax(silu(h) @ w2.T + b2)
  sgemm<false>(p.w1T, p.b1_f, xs, vnb, lane, ntb, acc);
  float ps[4], ps2[4];
  #pragma unroll
  for (int q=0;q<4;q++){
    ps[q]  = acc[0][q]+acc[1][q]+acc[2][q]+acc[3][q];
    ps2[q] = acc[0][q]*acc[0][q]+acc[1][q]*acc[1][q]+acc[2][q]*acc[2][q]+acc[3][q]*acc[3][q];
    ps[q] = wsum(ps[q]); ps2[q] = wsum(ps2[q]);
  }
  #pragma unroll
  for (int q=0;q<4;q++){
    float mu = ps[q]*(1.f/256.f);
    float var = ps2[q]*(1.f/256.f) - mu*mu;
    float rs = rsqrtf(var + 1e-5f);
    float h0 = (acc[0][q]-mu)*rs*p.lng_f[lane*4+0] + p.lnb_f[lane*4+0];
    float h1 = (acc[1][q]-mu)*rs*p.lng_f[lane*4+1] + p.lnb_f[lane*4+1];
    float h2 = (acc[2][q]-mu)*rs*p.lng_f[lane*4+2] + p.lnb_f[lane*4+2];
    float h3 = (acc[3][q]-mu)*rs*p.lng_f[lane*4+3] + p.lnb_f[lane*4+3];
    float4 hv = make_float4(siluf(h0), siluf(h1), siluf(h2), siluf(h3));
    *reinterpret_cast<float4*>(&sg[(ntb+q)*256 + lane*4]) = hv;
  }
  __syncthreads();
  float u4[4];
  gemm64(p.w2T, sg, lane, ntb, u4);
  #pragma unroll
  for (int q=0;q<4;q++) u4[q] += p.b2_f[lane];
  #pragma unroll
  for (int q=0;q<4;q++){
    float m = wmax(u4[q]);
    float e = __expf(u4[q]-m);
    float ss = wsum(e);
    p.Pm[(size_t)(n0+ntb+q)*64 + lane] = e/ss;
  }
}

// ---------------- k2: per-batch anchor compression (segmented + atomics) -----
__global__ __launch_bounds__(256) void k2(GP p){
  const int tid = threadIdx.x;
  const int bx = blockIdx.x;
  const int chunk = bx & 63, tile = bx >> 6;    // 64 chunks x 14 feature tiles
  const int n0 = chunk * 1024;
  const u16* src; int sst, soff, fbase; bool isCK;
  if (tile < 4)      { src=p.Ks; sst=256; soff=tile*64;      isCK=true;  fbase=soff;      }
  else if (tile < 7) { src=p.Kv; sst=192; soff=(tile-4)*64;  isCK=true;  fbase=256+soff;  }
  else if (tile < 11){ src=p.Vs; sst=256; soff=(tile-7)*64;  isCK=false; fbase=soff;      }
  else               { src=p.Vv; sst=192; soff=(tile-11)*64; isCK=false; fbase=256+soff;  }
  const int fl = tid&63, rg = tid>>6;
  __shared__ __align__(16) float Pl[1024];
  __shared__ __align__(16) float Fl[1024];
  __shared__ int Bl[16];
  float acc[16];
  #pragma unroll
  for (int j=0;j<16;j++) acc[j]=0.f;
  int curb = p.bidx[n0];

  for (int base=0; base<1024; base+=16){
    __syncthreads();
    for (int idx=tid; idx<1024; idx+=256){
      int nn = idx>>6, f = idx&63;
      Pl[idx] = p.Pm[(size_t)(n0+base+nn)*64 + f];
      Fl[idx] = b2f(src[(size_t)(n0+base+nn)*sst + soff + f]);
    }
    if (tid < 16) Bl[tid] = p.bidx[n0+base+tid];
    __syncthreads();
    for (int nn=0; nn<16; nn++){
      int b = Bl[nn];
      if (b != curb){
        if (isCK){
          int basei = (curb*448 + fbase + fl)*64 + rg*16;
          #pragma unroll
          for (int j=0;j<16;j++){ atomicAdd(&p.CK[basei+j], acc[j]); acc[j]=0.f; }
        } else {
          int rb = curb*64 + rg*16;
          #pragma unroll
          for (int j=0;j<16;j++){ atomicAdd(&p.CV[(rb+j)*448 + fbase + fl], acc[j]); acc[j]=0.f; }
        }
        curb = b;
      }
      float x = Fl[nn*64 + fl];
      float4 p0 = *reinterpret_cast<const float4*>(&Pl[nn*64 + rg*16 + 0]);
      float4 p1 = *reinterpret_cast<const float4*>(&Pl[nn*64 + rg*16 + 4]);
      float4 p2 = *reinterpret_cast<const float4*>(&Pl[nn*64 + rg*16 + 8]);
      float4 p3 = *reinterpret_cast<const float4*>(&Pl[nn*64 + rg*16 + 12]);
      acc[0]+=p0.x*x;  acc[1]+=p0.y*x;  acc[2]+=p0.z*x;  acc[3]+=p0.w*x;
      acc[4]+=p1.x*x;  acc[5]+=p1.y*x;  acc[6]+=p1.z*x;  acc[7]+=p1.w*x;
      acc[8]+=p2.x*x;  acc[9]+=p2.y*x;  acc[10]+=p2.z*x; acc[11]+=p2.w*x;
      acc[12]+=p3.x*x; acc[13]+=p3.y*x; acc[14]+=p3.z*x; acc[15]+=p3.w*x;
    }
  }
  if (isCK){
    int basei = (curb*448 + fbase + fl)*64 + rg*16;
    #pragma unroll
    for (int j=0;j<16;j++) atomicAdd(&p.CK[basei+j], acc[j]);
  } else {
    int rb = curb*64 + rg*16;
    #pragma unroll
    for (int j=0;j<16;j++) atomicAdd(&p.CV[(rb+j)*448 + fbase + fl], acc[j]);
  }
}

// ---------------- k3: attention + gating + output GVP ------------------------
__global__ __launch_bounds__(256) void k3(GP p){
  const int tid = threadIdx.x;
  const int n0 = blockIdx.x * 16;
  const int lane = tid & 63, ng = tid >> 6, ntb = ng*4;
  __shared__ __align__(16) float Qsl[4096];
  __shared__ __align__(16) float Qvl[3072];
  __shared__ __align__(16) float at[1024];
  __shared__ __align__(16) float vhb[3072];
  __shared__ __align__(16) float vnb[1024];
  __shared__ __align__(16) float sg[4096];
  __shared__ int Bl[16];

  for (int idx=tid; idx<4096; idx+=256){
    int nt=idx>>8, j=idx&255;
    Qsl[idx] = p.Qs[(size_t)(n0+nt)*256 + j];
  }
  for (int idx=tid; idx<3072; idx+=256){
    int nt=idx/192, k=idx-nt*192;
    Qvl[idx] = p.Qv[(size_t)(n0+nt)*192 + k];
  }
  if (tid<16) Bl[tid] = p.bidx[n0+tid];
  __syncthreads();

  // logits (thread: r=lane) + per-wave softmax over 64 anchors
  float lg[4];
  #pragma unroll 1
  for (int q=0;q<4;q++){
    int b = Bl[ntb+q];
    const float* CKb = p.CK + (size_t)b*448*64;
    float a = 0.f;
    for (int f4=0; f4<256; f4+=4){
      float w0=CKb[(f4+0)*64+lane], w1=CKb[(f4+1)*64+lane],
            w2=CKb[(f4+2)*64+lane], w3=CKb[(f4+3)*64+lane];
      float4 x = *reinterpret_cast<const float4*>(&Qsl[(ntb+q)*256 + f4]);
      a += x.x*w0 + x.y*w1 + x.z*w2 + x.w*w3;
    }
    const float* CKv = CKb + 256*64;
    for (int f4=0; f4<192; f4+=4){
      float w0=CKv[(f4+0)*64+lane], w1=CKv[(f4+1)*64+lane],
            w2=CKv[(f4+2)*64+lane], w3=CKv[(f4+3)*64+lane];
      float4 x = *reinterpret_cast<const float4*>(&Qvl[(ntb+q)*192 + f4]);
      a += x.x*w0 + x.y*w1 + x.z*w2 + x.w*w3;
    }
    lg[q] = a * 0.047245559f;     // 1/sqrt(448)
  }
  #pragma unroll
  for (int q=0;q<4;q++){
    float m = wmax(lg[q]);
    float e = __expf(lg[q]-m);
    float ss = wsum(e);
    at[(ntb+q)*64 + lane] = e/ss;
  }
  __syncthreads();

  // out_s (thread: i=lane*4..+3)
  float os[4][4];
  #pragma unroll
  for (int ii=0;ii<4;ii++){os[ii][0]=0;os[ii][1]=0;os[ii][2]=0;os[ii][3]=0;}
  #pragma unroll 1
  for (int q=0;q<4;q++){
    int b = Bl[ntb+q];
    const float* CVb = p.CV + (size_t)b*64*448;
    for (int r=0;r<64;r++){
      float w = at[(ntb+q)*64 + r];
      float4 v = *reinterpret_cast<const float4*>(&CVb[r*448 + lane*4]);
      os[0][q]+=v.x*w; os[1][q]+=v.y*w; os[2][q]+=v.z*w; os[3][q]+=v.w*w;
    }
  }
  // out_v (thread: d=lane)
  float ov[3][4];
  #pragma unroll
  for (int c=0;c<3;c++){ov[c][0]=0;ov[c][1]=0;ov[c][2]=0;ov[c][3]=0;}
  #pragma unroll 1
  for (int q=0;q<4;q++){
    int b = Bl[ntb+q];
    const float* CVv = p.CV + (size_t)b*64*448 + 256;
    for (int r=0;r<64;r++){
      float w = at[(ntb+q)*64 + r];
      ov[0][q] += CVv[r*448 + lane]*w;
      ov[1][q] += CVv[r*448 + 64 + lane]*w;
      ov[2][q] += CVv[r*448 + 128 + lane]*w;
    }
  }
  // gating -> s_in/v_in back into LDS (Qsl/Qvl reuse)
  #pragma unroll
  for (int q=0;q<4;q++){
    int n = n0 + ntb + q;
    ushort4 gu = *reinterpret_cast<const ushort4*>(&p.Gs[(size_t)n*256 + lane*4]);
    float4 sv = make_float4(os[0][q]*b2f(gu.x), os[1][q]*b2f(gu.y),
                            os[2][q]*b2f(gu.z), os[3][q]*b2f(gu.w));
    *reinterpret_cast<float4*>(&Qsl[(ntb+q)*256 + lane*4]) = sv;
    float gv = p.Gv[n];
    Qvl[(ntb+q)*192 + lane]       = ov[0][q]*gv;
    Qvl[(ntb+q)*192 + 64 + lane]  = ov[1][q]*gv;
    Qvl[(ntb+q)*192 + 128 + lane] = ov[2][q]*gv;
  }
  __syncthreads();

  // output GVP (set 4 = o)
  gvp_vh(p.whT + 4*4096, Qvl, vhb, lane, ntb);
  __syncthreads();
  calc_vn(vhb, vnb, tid);
  __syncthreads();
  float acc[4][4];
  sgemm<true>(p.wsT + (size_t)4*81920, p.wsb_f + 4*256, Qsl, vnb, lane, ntb, acc);
  #pragma unroll
  for (int q=0;q<4;q++){
    int n = n0 + ntb + q;
    float4 sl = make_float4(siluf(acc[0][q]), siluf(acc[1][q]),
                            siluf(acc[2][q]), siluf(acc[3][q]));
    *reinterpret_cast<float4*>(&p.Qs[(size_t)n*256 + lane*4]) = sl;
    float4 sv = make_float4(sigm(acc[0][q]), sigm(acc[1][q]),
                            sigm(acc[2][q]), sigm(acc[3][q]));
    *reinterpret_cast<float4*>(&sg[(ntb+q)*256 + lane*4]) = sv;
  }
  __syncthreads();
  float g4[4];
  gemm64(p.wsvT + 3*16384, sg, lane, ntb, g4);
  #pragma unroll
  for (int q=0;q<4;q++) g4[q] = sigm(g4[q] + p.wsvb_f[3*64 + lane]);
  float vo[3][4];
  gemmWv(p.wvT + 3*4096, vhb, lane, ntb, vo);
  #pragma unroll
  for (int q=0;q<4;q++){
    int n = n0 + ntb + q;
    #pragma unroll
    for (int c=0;c<3;c++)
      p.Qv[(size_t)n*192 + lane*3 + c] = vo[c][q]*g4[q];  // [N,DV,3] layout
  }
}

// ---------------- host ------------------------------------------------------
extern "C" void kernel_launch(void* const* d_in, const int* in_sizes, int n_in,
                              void* d_out, int out_size, void* d_ws, size_t ws_size,
                              hipStream_t stream){
  (void)in_sizes; (void)n_in; (void)out_size; (void)ws_size;
  GP p;
  p.x_s  = (const float*)d_in[0];
  p.x_v  = (const float*)d_in[1];
  p.bidx = (const int*)d_in[2];
  // set order: 0=q 1=k 2=v 3=g 4=o  (wv/wsv: 0=q 1=k 2=v 3=o)
  const int whI[5]  = {3, 9, 15, 33, 21};
  const int wswI[5] = {4, 10, 16, 34, 22};
  const int wsbI[5] = {5, 11, 17, 35, 23};
  const int wvI[4]  = {6, 12, 18, 24};
  const int wsvwI[4]= {7, 13, 19, 25};
  const int wsvbI[4]= {8, 14, 20, 26};
  for (int s=0;s<5;s++){
    p.wh[s]   = (const float*)d_in[whI[s]];
    p.ws_w[s] = (const float*)d_in[wswI[s]];
    p.ws_b[s] = (const float*)d_in[wsbI[s]];
  }
  for (int s=0;s<4;s++){
    p.wv[s]    = (const float*)d_in[wvI[s]];
    p.wsv_w[s] = (const float*)d_in[wsvwI[s]];
    p.wsv_b[s] = (const float*)d_in[wsvbI[s]];
  }
  p.w1    = (const float*)d_in[27];
  p.b1    = (const float*)d_in[28];
  p.lng   = (const float*)d_in[29];
  p.lnb   = (const float*)d_in[30];
  p.w2    = (const float*)d_in[31];
  p.b2    = (const float*)d_in[32];
  p.gbias = (const float*)d_in[36];

  char* w = (char*)d_ws;
  auto alloc = [&](size_t bytes)->char*{
    char* r = w; w += (bytes + 255) & ~(size_t)255; return r;
  };
  p.wsT   = (u16*)alloc(409600u*2);
  p.whT   = (u16*)alloc(20480u*2);
  p.wvT   = (u16*)alloc(16384u*2);
  p.wsvT  = (u16*)alloc(65536u*2);
  p.w1T   = (u16*)alloc(65536u*2);
  p.w2T   = (u16*)alloc(16384u*2);
  p.wsb_f  = (float*)alloc(1280u*4);
  p.wsvb_f = (float*)alloc(256u*4);
  p.b1_f   = (float*)alloc(256u*4);
  p.b2_f   = (float*)alloc(64u*4);
  p.lng_f  = (float*)alloc(256u*4);
  p.lnb_f  = (float*)alloc(256u*4);
  p.gb_f   = (float*)alloc(256u*4);
  p.Ks = (u16*)alloc((size_t)65536*256*2);
  p.Vs = (u16*)alloc((size_t)65536*256*2);
  p.Kv = (u16*)alloc((size_t)65536*192*2);
  p.Vv = (u16*)alloc((size_t)65536*192*2);
  p.Gs = (u16*)alloc((size_t)65536*256*2);
  p.Pm = (float*)alloc((size_t)65536*64*4);
  p.Gv = (float*)alloc((size_t)65536*4);
  p.CK = (float*)alloc((size_t)8*448*64*4);
  p.CV = (float*)alloc((size_t)8*448*64*4);
  p.Qs = (float*)d_out;
  p.Qv = (float*)d_out + (size_t)65536*256;

  hipMemsetAsync(p.CK, 0, (size_t)8*448*64*4, stream);
  hipMemsetAsync(p.CV, 0, (size_t)8*448*64*4, stream);
  kprep<<<2331, 256, 0, stream>>>(p);
  k1<<<4096, 256, 0, stream>>>(p);
  k2<<<896, 256, 0, stream>>>(p);
  k3<<<4096, 256, 0, stream>>>(p);
}

// Round 3
// 1842.408 us; speedup vs baseline: 2.1867x; 2.1867x over previous
//
#include <hip/hip_runtime.h>

typedef unsigned short u16;
typedef __attribute__((ext_vector_type(8))) short bs8;
typedef __attribute__((ext_vector_type(4))) float fx4;
#define MFMA16(a,b,c) __builtin_amdgcn_mfma_f32_16x16x32_bf16(a,b,c,0,0,0)

__device__ __forceinline__ float b2f(u16 u){ return __uint_as_float(((unsigned int)u) << 16); }
__device__ __forceinline__ u16 f2b(float f){
  unsigned int x = __float_as_uint(f);
  unsigned int r = (x + 0x7FFFu + ((x >> 16) & 1u)) >> 16;
  return (u16)r;
}
__device__ __forceinline__ float sigm(float x){ return 1.f/(1.f+__expf(-x)); }
__device__ __forceinline__ float siluf(float x){ return x/(1.f+__expf(-x)); }
__device__ __forceinline__ float wsum(float v){
  #pragma unroll
  for (int o=1;o<64;o<<=1) v += __shfl_xor(v, o);
  return v;
}
__device__ __forceinline__ float wmax(float v){
  #pragma unroll
  for (int o=1;o<64;o<<=1) v = fmaxf(v, __shfl_xor(v, o));
  return v;
}
__device__ __forceinline__ bs8 lds8(const u16* ptr){ return *reinterpret_cast<const bs8*>(ptr); }
__device__ __forceinline__ bs8 glb8(const u16* ptr){ return *reinterpret_cast<const bs8*>(ptr); }

// LDS strides (elements): chosen so row pitch mod 32 banks rotates by 4
#define XSB_P 328   // [16][328] bf16 : cols 0..255 xs, 256..319 vn
#define XVB_P 72    // [48][72]  bf16 : row = c*16+node, col = d/h
#define SGB_P 264   // [16][264] bf16
#define UBUF_P 68   // [16][68]  f32

struct GP {
  const float* x_s; const float* x_v; const int* bidx;
  const float* wh[5]; const float* ws_w[5]; const float* ws_b[5];
  const float* wv[4]; const float* wsv_w[4]; const float* wsv_b[4];
  const float *w1, *b1, *lng, *lnb, *w2, *b2, *gbias;
  u16 *wsP, *whP, *wvP, *wsvP, *w1P, *w2P;   // MFMA-B-fragment packed bf16
  float *wsb_f, *wsvb_f, *b1_f, *b2_f, *lng_f, *lnb_f, *gb_f;
  u16 *Ks, *Vs, *Kv, *Vv, *Gs;
  float *Pm, *Gv, *CK, *CV;
  float *Qs, *Qv;   // live inside d_out (f32 scratch, overwritten with final output)
};

// ---------- prep: pack weights into MFMA B-fragment order, biases f32 --------
// B-frag: element (kstep,ntile,lane,j) = W_orig[n = ntile*16+(lane&15)][k = kstep*32+(lane>>4)*8+j]
__global__ __launch_bounds__(256) void kprep(GP p){
  int idx = blockIdx.x*256 + threadIdx.x;
  if (idx < 409600){            // wsP: 5 sets, K=320 (10 ks), N=256 (16 nt)
    int s=idx/81920, r=idx%81920;
    int ks=r/8192, r2=r%8192, nt=r2/512, r3=r2%512, ln=r3/8, j=r3%8;
    int n=nt*16+(ln&15), k=ks*32+((ln>>4)*8)+j;
    p.wsP[idx] = f2b(p.ws_w[s][n*320+k]); return;
  }
  idx -= 409600;
  if (idx < 20480){             // whP: 5 sets, K=64 (2 ks), N=64 (4 nt)
    int s=idx/4096, r=idx%4096;
    int ks=r/2048, r2=r%2048, nt=r2/512, r3=r2%512, ln=r3/8, j=r3%8;
    int h=nt*16+(ln&15), d=ks*32+((ln>>4)*8)+j;
    p.whP[idx] = f2b(p.wh[s][h*64+d]); return;
  }
  idx -= 20480;
  if (idx < 16384){             // wvP: 4 sets, K=64, N=64
    int s=idx/4096, r=idx%4096;
    int ks=r/2048, r2=r%2048, nt=r2/512, r3=r2%512, ln=r3/8, j=r3%8;
    int dd=nt*16+(ln&15), hh=ks*32+((ln>>4)*8)+j;
    p.wvP[idx] = f2b(p.wv[s][dd*64+hh]); return;
  }
  idx -= 16384;
  if (idx < 65536){             // wsvP: 4 sets, K=256 (8 ks), N=64 (4 nt)
    int s=idx/16384, r=idx%16384;
    int ks=r/2048, r2=r%2048, nt=r2/512, r3=r2%512, ln=r3/8, j=r3%8;
    int dd=nt*16+(ln&15), i=ks*32+((ln>>4)*8)+j;
    p.wsvP[idx] = f2b(p.wsv_w[s][dd*256+i]); return;
  }
  idx -= 65536;
  if (idx < 65536){             // w1P: K=256 (8 ks), N=256 (16 nt)
    int ks=idx/8192, r2=idx%8192, nt=r2/512, r3=r2%512, ln=r3/8, j=r3%8;
    int n=nt*16+(ln&15), k=ks*32+((ln>>4)*8)+j;
    p.w1P[idx] = f2b(p.w1[n*256+k]); return;
  }
  idx -= 65536;
  if (idx < 16384){             // w2P: K=256 (8 ks), N=64 (4 nt)
    int ks=idx/2048, r2=idx%2048, nt=r2/512, r3=r2%512, ln=r3/8, j=r3%8;
    int rr=nt*16+(ln&15), i=ks*32+((ln>>4)*8)+j;
    p.w2P[idx] = f2b(p.w2[rr*256+i]); return;
  }
  idx -= 16384;
  if (idx < 1280){ int s=idx>>8, i=idx&255; p.wsb_f[idx] = p.ws_b[s][i]; return; }
  idx -= 1280;
  if (idx < 256){ int s=idx>>6, d=idx&63; p.wsvb_f[idx] = p.wsv_b[s][d]; return; }
  idx -= 256;
  if (idx < 256){ p.b1_f[idx] = p.b1[idx]; return; }
  idx -= 256;
  if (idx < 64){ p.b2_f[idx] = p.b2[idx]; return; }
  idx -= 64;
  if (idx < 256){ p.lng_f[idx] = p.lng[idx]; return; }
  idx -= 256;
  if (idx < 256){ p.lnb_f[idx] = p.lnb[idx]; return; }
  idx -= 256;
  if (idx < 256){ p.gb_f[idx] = p.gbias[idx]; return; }
}

// ---------------- MFMA building blocks (16 nodes / block, 4 waves) ----------
// vh = xv @ wh^T (M=48 rows c*16+node, K=64, N=64); then vn -> xsb[:,256..319]
__device__ __forceinline__ void mfma_vh_vn(const u16* whPs, const u16* xvb, u16* vhb2,
                                           u16* xsb, int lane, int wave, int tid){
  fx4 a0={0,0,0,0}, a1={0,0,0,0}, a2={0,0,0,0};
  #pragma unroll
  for (int ks=0; ks<2; ks++){
    bs8 b = glb8(whPs + (ks*4+wave)*512 + lane*8);
    bs8 x0 = lds8(xvb + ( 0 + (lane&15))*XVB_P + ks*32 + ((lane>>4)*8));
    bs8 x1 = lds8(xvb + (16 + (lane&15))*XVB_P + ks*32 + ((lane>>4)*8));
    bs8 x2 = lds8(xvb + (32 + (lane&15))*XVB_P + ks*32 + ((lane>>4)*8));
    a0 = MFMA16(x0,b,a0); a1 = MFMA16(x1,b,a1); a2 = MFMA16(x2,b,a2);
  }
  int h = wave*16 + (lane&15);
  int mrow = (lane>>4)*4;
  #pragma unroll
  for (int r=0;r<4;r++){
    vhb2[( 0+mrow+r)*XVB_P + h] = f2b(a0[r]);
    vhb2[(16+mrow+r)*XVB_P + h] = f2b(a1[r]);
    vhb2[(32+mrow+r)*XVB_P + h] = f2b(a2[r]);
  }
  __syncthreads();
  for (int i=tid; i<1024; i+=256){
    int node=i>>6, hh=i&63;
    float a=b2f(vhb2[node*XVB_P+hh]);
    float b=b2f(vhb2[(16+node)*XVB_P+hh]);
    float c=b2f(vhb2[(32+node)*XVB_P+hh]);
    xsb[node*XSB_P + 256 + hh] = f2b(sqrtf(fmaxf(a*a+b*b+c*c, 1e-8f)));
  }
  __syncthreads();
}

// s_out = cat(xs,vn) @ W^T + b  (M=16, K=32*KS, N=256); wave handles ntiles wave*4..+3
template<int KS>
__device__ __forceinline__ void mfma_sgemm(const u16* wsPs, const float* bias,
                                           const u16* xsb, int lane, int wave, fx4 acc[4]){
  #pragma unroll
  for (int t=0;t<4;t++) acc[t] = (fx4){0.f,0.f,0.f,0.f};
  const u16* arow = xsb + (lane&15)*XSB_P + ((lane>>4)*8);
  #pragma unroll
  for (int ks=0; ks<KS; ks++){
    bs8 a = lds8(arow + ks*32);
    #pragma unroll
    for (int t=0;t<4;t++){
      bs8 b = glb8(wsPs + (ks*16 + wave*4 + t)*512 + lane*8);
      acc[t] = MFMA16(a,b,acc[t]);
    }
  }
  #pragma unroll
  for (int t=0;t<4;t++){
    float bv = bias[(wave*4+t)*16 + (lane&15)];
    acc[t][0]+=bv; acc[t][1]+=bv; acc[t][2]+=bv; acc[t][3]+=bv;
  }
}

// out64 = sgb @ W^T  (M=16, K=256, N=64); wave handles ntile=wave
__device__ __forceinline__ fx4 mfma_g64(const u16* bP, const u16* sgb, int lane, int wave){
  fx4 acc = {0.f,0.f,0.f,0.f};
  const u16* arow = sgb + (lane&15)*SGB_P + ((lane>>4)*8);
  #pragma unroll
  for (int ks=0; ks<8; ks++){
    bs8 a = lds8(arow + ks*32);
    bs8 b = glb8(bP + (ks*4 + wave)*512 + lane*8);
    acc = MFMA16(a,b,acc);
  }
  return acc;
}

// vo = vh @ wv^T (M=48, K=64, N=64); wave handles ntile=wave
__device__ __forceinline__ void mfma_wv(const u16* wvPs, const u16* vhb2,
                                        int lane, int wave, fx4 vo[3]){
  vo[0]=(fx4){0.f,0.f,0.f,0.f}; vo[1]=vo[0]; vo[2]=vo[0];
  #pragma unroll
  for (int ks=0; ks<2; ks++){
    bs8 b = glb8(wvPs + (ks*4+wave)*512 + lane*8);
    #pragma unroll
    for (int c=0;c<3;c++){
      bs8 a = lds8(vhb2 + (c*16 + (lane&15))*XVB_P + ks*32 + ((lane>>4)*8));
      vo[c] = MFMA16(a,b,vo[c]);
    }
  }
}

// ---------------- k1: q/k/v/g GVPs + comp path (16 nodes / block) -----------
__global__ __launch_bounds__(256) void k1(GP p){
  __shared__ __align__(16) u16 xsb[16*XSB_P];
  __shared__ __align__(16) u16 xvb[48*XVB_P];
  __shared__ __align__(16) u16 vhb2[48*XVB_P];
  __shared__ __align__(16) u16 sgb[16*SGB_P];
  __shared__ float red[8][16];
  __shared__ float lnp[2][16];
  __shared__ float ubuf[16*UBUF_P];
  const int tid = threadIdx.x, lane = tid&63, wave = tid>>6;
  const int n0 = blockIdx.x * 16;

  for (int i=tid;i<1024;i+=256){
    int node=i>>6, c4=(i&63)*4;
    float4 v = *reinterpret_cast<const float4*>(p.x_s + (size_t)(n0+node)*256 + c4);
    u16* d = xsb + node*XSB_P + c4;
    d[0]=f2b(v.x); d[1]=f2b(v.y); d[2]=f2b(v.z); d[3]=f2b(v.w);
  }
  for (int i=tid;i<3072;i+=256){
    int row=i>>6, d=i&63, c=row>>4, node=row&15;
    xvb[row*XVB_P+d] = f2b(p.x_v[(size_t)(n0+node)*192 + d*3 + c]);
  }
  __syncthreads();

  fx4 acc[4];
  #pragma unroll 1
  for (int s=0; s<3; ++s){      // 0=q 1=k 2=v
    mfma_vh_vn(p.whP + s*4096, xvb, vhb2, xsb, lane, wave, tid);
    mfma_sgemm<10>(p.wsP + (size_t)s*81920, p.wsb_f + s*256, xsb, lane, wave, acc);
    u16* KVs = (s==1) ? p.Ks : p.Vs;
    #pragma unroll
    for (int t=0;t<4;t++){
      int ncol=(wave*4+t)*16+(lane&15);
      #pragma unroll
      for (int r=0;r<4;r++){
        int node=((lane>>4)*4)+r;
        float v=acc[t][r];
        float sl=siluf(v);
        if (s==0) p.Qs[(size_t)(n0+node)*256+ncol]=sl;
        else      KVs[(size_t)(n0+node)*256+ncol]=f2b(sl);
        sgb[node*SGB_P+ncol]=f2b(sigm(v));
      }
    }
    __syncthreads();
    fx4 g = mfma_g64(p.wsvP + s*16384, sgb, lane, wave);
    fx4 vo[3];
    mfma_wv(p.wvP + s*4096, vhb2, lane, wave, vo);
    int dout = wave*16+(lane&15);
    #pragma unroll
    for (int r=0;r<4;r++){
      int node=((lane>>4)*4)+r;
      float gg = sigm(g[r] + p.wsvb_f[s*64+dout]);
      if (s==0){
        #pragma unroll
        for (int c=0;c<3;c++)
          p.Qv[(size_t)(n0+node)*192 + c*64 + dout] = vo[c][r]*gg;
      } else {
        u16* KVv=(s==1)?p.Kv:p.Vv;
        #pragma unroll
        for (int c=0;c<3;c++)
          KVv[(size_t)(n0+node)*192 + c*64 + dout] = f2b(vo[c][r]*gg);
      }
    }
    __syncthreads();
  }

  // gate set
  mfma_vh_vn(p.whP + 3*4096, xvb, vhb2, xsb, lane, wave, tid);
  mfma_sgemm<10>(p.wsP + (size_t)3*81920, p.wsb_f + 3*256, xsb, lane, wave, acc);
  {
    float psum[4] = {0.f,0.f,0.f,0.f};
    #pragma unroll
    for (int t=0;t<4;t++){
      int ncol=(wave*4+t)*16+(lane&15);
      float gb = p.gb_f[ncol];
      #pragma unroll
      for (int r=0;r<4;r++){
        int node=((lane>>4)*4)+r;
        float gs = sigm(acc[t][r] + gb);
        p.Gs[(size_t)(n0+node)*256+ncol] = f2b(gs);
        psum[r] += gs;
      }
    }
    #pragma unroll
    for (int r=0;r<4;r++){
      #pragma unroll
      for (int o=1;o<16;o<<=1) psum[r] += __shfl_xor(psum[r], o);
    }
    if ((lane&15)==0){
      #pragma unroll
      for (int r=0;r<4;r++) red[wave][((lane>>4)*4)+r] = psum[r];
    }
    __syncthreads();
    if (tid<16)
      p.Gv[n0+tid] = sigm((red[0][tid]+red[1][tid]+red[2][tid]+red[3][tid])*(1.f/256.f));
    __syncthreads();
  }

  // comp path: h = LN(xs @ w1^T + b1); P = softmax(silu(h) @ w2^T + b2)
  mfma_sgemm<8>(p.w1P, p.b1_f, xsb, lane, wave, acc);
  {
    float s1[4]={0.f,0.f,0.f,0.f}, s2[4]={0.f,0.f,0.f,0.f};
    #pragma unroll
    for (int t=0;t<4;t++)
      #pragma unroll
      for (int r=0;r<4;r++){ float v=acc[t][r]; s1[r]+=v; s2[r]+=v*v; }
    #pragma unroll
    for (int r=0;r<4;r++){
      #pragma unroll
      for (int o=1;o<16;o<<=1){ s1[r]+=__shfl_xor(s1[r],o); s2[r]+=__shfl_xor(s2[r],o); }
    }
    if ((lane&15)==0){
      #pragma unroll
      for (int r=0;r<4;r++){
        red[wave][((lane>>4)*4)+r]=s1[r];
        red[4+wave][((lane>>4)*4)+r]=s2[r];
      }
    }
    __syncthreads();
    if (tid<16){
      float S1=red[0][tid]+red[1][tid]+red[2][tid]+red[3][tid];
      float S2=red[4][tid]+red[5][tid]+red[6][tid]+red[7][tid];
      float mu=S1*(1.f/256.f), var=S2*(1.f/256.f)-mu*mu;
      lnp[0][tid]=mu; lnp[1][tid]=rsqrtf(var+1e-5f);
    }
    __syncthreads();
    #pragma unroll
    for (int t=0;t<4;t++){
      int ncol=(wave*4+t)*16+(lane&15);
      float g=p.lng_f[ncol], b=p.lnb_f[ncol];
      #pragma unroll
      for (int r=0;r<4;r++){
        int node=((lane>>4)*4)+r;
        float h=(acc[t][r]-lnp[0][node])*lnp[1][node]*g + b;
        sgb[node*SGB_P+ncol]=f2b(siluf(h));
      }
    }
    __syncthreads();
    fx4 u = mfma_g64(p.w2P, sgb, lane, wave);
    int rcol = wave*16+(lane&15);
    float b2v = p.b2_f[rcol];
    #pragma unroll
    for (int r=0;r<4;r++)
      ubuf[(((lane>>4)*4)+r)*UBUF_P + rcol] = u[r] + b2v;
    __syncthreads();
    #pragma unroll
    for (int i=0;i<4;i++){
      int node = wave*4+i;
      float uu = ubuf[node*UBUF_P + lane];
      float m = wmax(uu);
      float e = __expf(uu-m);
      float ss = wsum(e);
      p.Pm[(size_t)(n0+node)*64 + lane] = e/ss;
    }
  }
}

// ---------------- k2: per-batch anchor compression (segmented + atomics) -----
__global__ __launch_bounds__(256) void k2(GP p){
  const int tid = threadIdx.x;
  const int bx = blockIdx.x;
  const int chunk = bx & 63, tile = bx >> 6;    // 64 chunks x 14 feature tiles
  const int n0 = chunk * 1024;
  const u16* src; int sst, soff, fbase; bool isCK;
  if (tile < 4)      { src=p.Ks; sst=256; soff=tile*64;      isCK=true;  fbase=soff;      }
  else if (tile < 7) { src=p.Kv; sst=192; soff=(tile-4)*64;  isCK=true;  fbase=256+soff;  }
  else if (tile < 11){ src=p.Vs; sst=256; soff=(tile-7)*64;  isCK=false; fbase=soff;      }
  else               { src=p.Vv; sst=192; soff=(tile-11)*64; isCK=false; fbase=256+soff;  }
  const int fl = tid&63, rg = tid>>6;
  __shared__ __align__(16) float Pl[1024];
  __shared__ __align__(16) float Fl[1024];
  __shared__ int Bl[16];
  float acc[16];
  #pragma unroll
  for (int j=0;j<16;j++) acc[j]=0.f;
  int curb = p.bidx[n0];

  for (int base=0; base<1024; base+=16){
    __syncthreads();
    for (int idx=tid; idx<1024; idx+=256){
      int nn = idx>>6, f = idx&63;
      Pl[idx] = p.Pm[(size_t)(n0+base+nn)*64 + f];
      Fl[idx] = b2f(src[(size_t)(n0+base+nn)*sst + soff + f]);
    }
    if (tid < 16) Bl[tid] = p.bidx[n0+base+tid];
    __syncthreads();
    for (int nn=0; nn<16; nn++){
      int b = Bl[nn];
      if (b != curb){
        if (isCK){
          int basei = (curb*448 + fbase + fl)*64 + rg*16;
          #pragma unroll
          for (int j=0;j<16;j++){ atomicAdd(&p.CK[basei+j], acc[j]); acc[j]=0.f; }
        } else {
          int rb = curb*64 + rg*16;
          #pragma unroll
          for (int j=0;j<16;j++){ atomicAdd(&p.CV[(rb+j)*448 + fbase + fl], acc[j]); acc[j]=0.f; }
        }
        curb = b;
      }
      float x = Fl[nn*64 + fl];
      float4 p0 = *reinterpret_cast<const float4*>(&Pl[nn*64 + rg*16 + 0]);
      float4 p1 = *reinterpret_cast<const float4*>(&Pl[nn*64 + rg*16 + 4]);
      float4 p2 = *reinterpret_cast<const float4*>(&Pl[nn*64 + rg*16 + 8]);
      float4 p3 = *reinterpret_cast<const float4*>(&Pl[nn*64 + rg*16 + 12]);
      acc[0]+=p0.x*x;  acc[1]+=p0.y*x;  acc[2]+=p0.z*x;  acc[3]+=p0.w*x;
      acc[4]+=p1.x*x;  acc[5]+=p1.y*x;  acc[6]+=p1.z*x;  acc[7]+=p1.w*x;
      acc[8]+=p2.x*x;  acc[9]+=p2.y*x;  acc[10]+=p2.z*x; acc[11]+=p2.w*x;
      acc[12]+=p3.x*x; acc[13]+=p3.y*x; acc[14]+=p3.z*x; acc[15]+=p3.w*x;
    }
  }
  if (isCK){
    int basei = (curb*448 + fbase + fl)*64 + rg*16;
    #pragma unroll
    for (int j=0;j<16;j++) atomicAdd(&p.CK[basei+j], acc[j]);
  } else {
    int rb = curb*64 + rg*16;
    #pragma unroll
    for (int j=0;j<16;j++) atomicAdd(&p.CV[(rb+j)*448 + fbase + fl], acc[j]);
  }
}

// ---------------- k3: attention + gating + output GVP (MFMA) -----------------
__global__ __launch_bounds__(256) void k3(GP p){
  __shared__ __align__(16) char smem[33536];
  float* Qsl = (float*)smem;            // phase1: [16*256] f32
  float* Qvl = (float*)(smem+16384);    // phase1: [16*192] f32
  float* at  = (float*)(smem+28672);    // phase1: [16*64]  f32
  u16* xsb   = (u16*)smem;              // phase2: [16*XSB_P]
  u16* xvb   = (u16*)(smem+10496);      // phase2: [48*XVB_P]
  u16* vhb2  = (u16*)(smem+17408);      // phase2: [48*XVB_P]
  u16* sgb   = (u16*)(smem+24320);      // phase2: [16*SGB_P] (aliases dead `at`)
  __shared__ int Bl[16];
  const int tid = threadIdx.x;
  const int n0 = blockIdx.x * 16;
  const int lane = tid & 63, wave = tid >> 6, ntb = wave*4;

  for (int idx=tid; idx<4096; idx+=256)
    Qsl[idx] = p.Qs[(size_t)(n0+(idx>>8))*256 + (idx&255)];
  for (int idx=tid; idx<3072; idx+=256){
    int nt=idx/192, k=idx-nt*192;
    Qvl[idx] = p.Qv[(size_t)(n0+nt)*192 + k];
  }
  if (tid<16) Bl[tid] = p.bidx[n0+tid];
  __syncthreads();

  // logits (thread: r=lane) + per-wave softmax over 64 anchors
  float lg[4];
  #pragma unroll 1
  for (int q=0;q<4;q++){
    int b = Bl[ntb+q];
    const float* CKb = p.CK + (size_t)b*448*64;
    float a = 0.f;
    for (int f4=0; f4<256; f4+=4){
      float w0=CKb[(f4+0)*64+lane], w1=CKb[(f4+1)*64+lane],
            w2=CKb[(f4+2)*64+lane], w3=CKb[(f4+3)*64+lane];
      float4 x = *reinterpret_cast<const float4*>(&Qsl[(ntb+q)*256 + f4]);
      a += x.x*w0 + x.y*w1 + x.z*w2 + x.w*w3;
    }
    const float* CKv = CKb + 256*64;
    for (int f4=0; f4<192; f4+=4){
      float w0=CKv[(f4+0)*64+lane], w1=CKv[(f4+1)*64+lane],
            w2=CKv[(f4+2)*64+lane], w3=CKv[(f4+3)*64+lane];
      float4 x = *reinterpret_cast<const float4*>(&Qvl[(ntb+q)*192 + f4]);
      a += x.x*w0 + x.y*w1 + x.z*w2 + x.w*w3;
    }
    lg[q] = a * 0.047245559f;     // 1/sqrt(448)
  }
  #pragma unroll
  for (int q=0;q<4;q++){
    float m = wmax(lg[q]);
    float e = __expf(lg[q]-m);
    float ss = wsum(e);
    at[(ntb+q)*64 + lane] = e/ss;
  }
  __syncthreads();

  // out_s (thread: i=lane*4..+3)
  float os[4][4];
  #pragma unroll
  for (int ii=0;ii<4;ii++){os[ii][0]=0;os[ii][1]=0;os[ii][2]=0;os[ii][3]=0;}
  #pragma unroll 1
  for (int q=0;q<4;q++){
    int b = Bl[ntb+q];
    const float* CVb = p.CV + (size_t)b*64*448;
    for (int r=0;r<64;r++){
      float w = at[(ntb+q)*64 + r];
      float4 v = *reinterpret_cast<const float4*>(&CVb[r*448 + lane*4]);
      os[0][q]+=v.x*w; os[1][q]+=v.y*w; os[2][q]+=v.z*w; os[3][q]+=v.w*w;
    }
  }
  // out_v (thread: d=lane)
  float ov[3][4];
  #pragma unroll
  for (int c=0;c<3;c++){ov[c][0]=0;ov[c][1]=0;ov[c][2]=0;ov[c][3]=0;}
  #pragma unroll 1
  for (int q=0;q<4;q++){
    int b = Bl[ntb+q];
    const float* CVv = p.CV + (size_t)b*64*448 + 256;
    for (int r=0;r<64;r++){
      float w = at[(ntb+q)*64 + r];
      ov[0][q] += CVv[r*448 + lane]*w;
      ov[1][q] += CVv[r*448 + 64 + lane]*w;
      ov[2][q] += CVv[r*448 + 128 + lane]*w;
    }
  }
  __syncthreads();   // phase 1 LDS dead; begin phase 2

  // gated s_in/v_in -> bf16 LDS fragments
  #pragma unroll
  for (int q=0;q<4;q++){
    int node = ntb+q;
    int n = n0 + node;
    ushort4 gu = *reinterpret_cast<const ushort4*>(&p.Gs[(size_t)n*256 + lane*4]);
    u16* d = xsb + node*XSB_P + lane*4;
    d[0]=f2b(os[0][q]*b2f(gu.x)); d[1]=f2b(os[1][q]*b2f(gu.y));
    d[2]=f2b(os[2][q]*b2f(gu.z)); d[3]=f2b(os[3][q]*b2f(gu.w));
    float gv = p.Gv[n];
    xvb[( 0+node)*XVB_P + lane] = f2b(ov[0][q]*gv);
    xvb[(16+node)*XVB_P + lane] = f2b(ov[1][q]*gv);
    xvb[(32+node)*XVB_P + lane] = f2b(ov[2][q]*gv);
  }
  __syncthreads();

  // output GVP (set 4 for wh/ws, set 3 for wv/wsv)
  mfma_vh_vn(p.whP + 4*4096, xvb, vhb2, xsb, lane, wave, tid);
  fx4 acc[4];
  mfma_sgemm<10>(p.wsP + (size_t)4*81920, p.wsb_f + 4*256, xsb, lane, wave, acc);
  #pragma unroll
  for (int t=0;t<4;t++){
    int ncol=(wave*4+t)*16+(lane&15);
    #pragma unroll
    for (int r=0;r<4;r++){
      int node=((lane>>4)*4)+r;
      float v=acc[t][r];
      p.Qs[(size_t)(n0+node)*256+ncol]=siluf(v);
      sgb[node*SGB_P+ncol]=f2b(sigm(v));
    }
  }
  __syncthreads();
  fx4 g = mfma_g64(p.wsvP + 3*16384, sgb, lane, wave);
  fx4 vo[3];
  mfma_wv(p.wvP + 3*4096, vhb2, lane, wave, vo);
  int dout = wave*16+(lane&15);
  #pragma unroll
  for (int r=0;r<4;r++){
    int node=((lane>>4)*4)+r;
    float gg = sigm(g[r] + p.wsvb_f[3*64+dout]);
    #pragma unroll
    for (int c=0;c<3;c++)
      p.Qv[(size_t)(n0+node)*192 + dout*3 + c] = vo[c][r]*gg;   // [N,DV,3]
  }
}

// ---------------- host ------------------------------------------------------
extern "C" void kernel_launch(void* const* d_in, const int* in_sizes, int n_in,
                              void* d_out, int out_size, void* d_ws, size_t ws_size,
                              hipStream_t stream){
  (void)in_sizes; (void)n_in; (void)out_size; (void)ws_size;
  GP p;
  p.x_s  = (const float*)d_in[0];
  p.x_v  = (const float*)d_in[1];
  p.bidx = (const int*)d_in[2];
  // set order: 0=q 1=k 2=v 3=g 4=o  (wv/wsv: 0=q 1=k 2=v 3=o)
  const int whI[5]  = {3, 9, 15, 33, 21};
  const int wswI[5] = {4, 10, 16, 34, 22};
  const int wsbI[5] = {5, 11, 17, 35, 23};
  const int wvI[4]  = {6, 12, 18, 24};
  const int wsvwI[4]= {7, 13, 19, 25};
  const int wsvbI[4]= {8, 14, 20, 26};
  for (int s=0;s<5;s++){
    p.wh[s]   = (const float*)d_in[whI[s]];
    p.ws_w[s] = (const float*)d_in[wswI[s]];
    p.ws_b[s] = (const float*)d_in[wsbI[s]];
  }
  for (int s=0;s<4;s++){
    p.wv[s]    = (const float*)d_in[wvI[s]];
    p.wsv_w[s] = (const float*)d_in[wsvwI[s]];
    p.wsv_b[s] = (const float*)d_in[wsvbI[s]];
  }
  p.w1    = (const float*)d_in[27];
  p.b1    = (const float*)d_in[28];
  p.lng   = (const float*)d_in[29];
  p.lnb   = (const float*)d_in[30];
  p.w2    = (const float*)d_in[31];
  p.b2    = (const float*)d_in[32];
  p.gbias = (const float*)d_in[36];

  char* w = (char*)d_ws;
  auto alloc = [&](size_t bytes)->char*{
    char* r = w; w += (bytes + 255) & ~(size_t)255; return r;
  };
  p.wsP   = (u16*)alloc(409600u*2);
  p.whP   = (u16*)alloc(20480u*2);
  p.wvP   = (u16*)alloc(16384u*2);
  p.wsvP  = (u16*)alloc(65536u*2);
  p.w1P   = (u16*)alloc(65536u*2);
  p.w2P   = (u16*)alloc(16384u*2);
  p.wsb_f  = (float*)alloc(1280u*4);
  p.wsvb_f = (float*)alloc(256u*4);
  p.b1_f   = (float*)alloc(256u*4);
  p.b2_f   = (float*)alloc(64u*4);
  p.lng_f  = (float*)alloc(256u*4);
  p.lnb_f  = (float*)alloc(256u*4);
  p.gb_f   = (float*)alloc(256u*4);
  p.Ks = (u16*)alloc((size_t)65536*256*2);
  p.Vs = (u16*)alloc((size_t)65536*256*2);
  p.Kv = (u16*)alloc((size_t)65536*192*2);
  p.Vv = (u16*)alloc((size_t)65536*192*2);
  p.Gs = (u16*)alloc((size_t)65536*256*2);
  p.Pm = (float*)alloc((size_t)65536*64*4);
  p.Gv = (float*)alloc((size_t)65536*4);
  p.CK = (float*)alloc((size_t)8*448*64*4);
  p.CV = (float*)alloc((size_t)8*448*64*4);
  p.Qs = (float*)d_out;
  p.Qv = (float*)d_out + (size_t)65536*256;

  hipMemsetAsync(p.CK, 0, (size_t)8*448*64*4, stream);
  hipMemsetAsync(p.CV, 0, (size_t)8*448*64*4, stream);
  kprep<<<2331, 256, 0, stream>>>(p);
  k1<<<4096, 256, 0, stream>>>(p);
  k2<<<896, 256, 0, stream>>>(p);
  k3<<<4096, 256, 0, stream>>>(p);
}

// Round 4
// 1219.907 us; speedup vs baseline: 3.3025x; 1.5103x over previous
//
#include <hip/hip_runtime.h>

typedef unsigned short u16;
typedef __attribute__((ext_vector_type(8))) short bs8;
typedef __attribute__((ext_vector_type(4))) float fx4;
#define MFMA16(a,b,c) __builtin_amdgcn_mfma_f32_16x16x32_bf16(a,b,c,0,0,0)

__device__ __forceinline__ float b2f(u16 u){ return __uint_as_float(((unsigned int)u) << 16); }
__device__ __forceinline__ u16 f2b(float f){
  unsigned int x = __float_as_uint(f);
  unsigned int r = (x + 0x7FFFu + ((x >> 16) & 1u)) >> 16;
  return (u16)r;
}
__device__ __forceinline__ float sigm(float x){ return 1.f/(1.f+__expf(-x)); }
__device__ __forceinline__ float siluf(float x){ return x/(1.f+__expf(-x)); }
__device__ __forceinline__ float wsum(float v){
  #pragma unroll
  for (int o=1;o<64;o<<=1) v += __shfl_xor(v, o);
  return v;
}
__device__ __forceinline__ float wmax(float v){
  #pragma unroll
  for (int o=1;o<64;o<<=1) v = fmaxf(v, __shfl_xor(v, o));
  return v;
}
__device__ __forceinline__ bs8 lds8(const u16* ptr){ return *reinterpret_cast<const bs8*>(ptr); }
__device__ __forceinline__ bs8 glb8(const u16* ptr){ return *reinterpret_cast<const bs8*>(ptr); }

// LDS strides (elements): row pitch mod 32 banks rotates by 4
#define XSB_P 328   // [16][328] bf16 : cols 0..255 xs, 256..319 vn
#define XVB_P 72    // [48][72]  bf16 : row = c*16+node, col = d/h
#define SGB_P 264   // [16][264] bf16
#define UBUF_P 68   // [16][68]  f32
#define XQ_P 456    // [16][456] bf16 : 448 q-features
#define AT_P 72     // [16][72]  bf16 : 64 anchors

struct GP {
  const float* x_s; const float* x_v; const int* bidx;
  const float* wh[5]; const float* ws_w[5]; const float* ws_b[5];
  const float* wv[4]; const float* wsv_w[4]; const float* wsv_b[4];
  const float *w1, *b1, *lng, *lnb, *w2, *b2, *gbias;
  u16 *wsP, *whP, *wvP, *wsvP, *w1P, *w2P;   // MFMA-B-fragment packed bf16
  float *wsb_f, *wsvb_f, *b1_f, *b2_f, *lng_f, *lnb_f, *gb_f;
  u16 *Ks, *Vs, *Kv, *Vv, *Gs;
  float *Pm, *Gv, *CK, *CV;
  u16 *CKP, *CVP;                            // packed bf16 B-frags for attention
  float *Qs, *Qv;   // live inside d_out (f32 scratch, overwritten with final output)
};

// ---------- prep: pack weights into MFMA B-fragment order, biases f32 --------
// B-frag: element (kstep,ntile,lane,j) = W_orig[n = ntile*16+(lane&15)][k = kstep*32+(lane>>4)*8+j]
__global__ __launch_bounds__(256) void kprep(GP p){
  int idx = blockIdx.x*256 + threadIdx.x;
  if (idx < 409600){            // wsP: 5 sets, K=320 (10 ks), N=256 (16 nt)
    int s=idx/81920, r=idx%81920;
    int ks=r/8192, r2=r%8192, nt=r2/512, r3=r2%512, ln=r3/8, j=r3%8;
    int n=nt*16+(ln&15), k=ks*32+((ln>>4)*8)+j;
    p.wsP[idx] = f2b(p.ws_w[s][n*320+k]); return;
  }
  idx -= 409600;
  if (idx < 20480){             // whP: 5 sets, K=64 (2 ks), N=64 (4 nt)
    int s=idx/4096, r=idx%4096;
    int ks=r/2048, r2=r%2048, nt=r2/512, r3=r2%512, ln=r3/8, j=r3%8;
    int h=nt*16+(ln&15), d=ks*32+((ln>>4)*8)+j;
    p.whP[idx] = f2b(p.wh[s][h*64+d]); return;
  }
  idx -= 20480;
  if (idx < 16384){             // wvP: 4 sets, K=64, N=64
    int s=idx/4096, r=idx%4096;
    int ks=r/2048, r2=r%2048, nt=r2/512, r3=r2%512, ln=r3/8, j=r3%8;
    int dd=nt*16+(ln&15), hh=ks*32+((ln>>4)*8)+j;
    p.wvP[idx] = f2b(p.wv[s][dd*64+hh]); return;
  }
  idx -= 16384;
  if (idx < 65536){             // wsvP: 4 sets, K=256 (8 ks), N=64 (4 nt)
    int s=idx/16384, r=idx%16384;
    int ks=r/2048, r2=r%2048, nt=r2/512, r3=r2%512, ln=r3/8, j=r3%8;
    int dd=nt*16+(ln&15), i=ks*32+((ln>>4)*8)+j;
    p.wsvP[idx] = f2b(p.wsv_w[s][dd*256+i]); return;
  }
  idx -= 65536;
  if (idx < 65536){             // w1P: K=256 (8 ks), N=256 (16 nt)
    int ks=idx/8192, r2=idx%8192, nt=r2/512, r3=r2%512, ln=r3/8, j=r3%8;
    int n=nt*16+(ln&15), k=ks*32+((ln>>4)*8)+j;
    p.w1P[idx] = f2b(p.w1[n*256+k]); return;
  }
  idx -= 65536;
  if (idx < 16384){             // w2P: K=256 (8 ks), N=64 (4 nt)
    int ks=idx/2048, r2=idx%2048, nt=r2/512, r3=r2%512, ln=r3/8, j=r3%8;
    int rr=nt*16+(ln&15), i=ks*32+((ln>>4)*8)+j;
    p.w2P[idx] = f2b(p.w2[rr*256+i]); return;
  }
  idx -= 16384;
  if (idx < 1280){ int s=idx>>8, i=idx&255; p.wsb_f[idx] = p.ws_b[s][i]; return; }
  idx -= 1280;
  if (idx < 256){ int s=idx>>6, d=idx&63; p.wsvb_f[idx] = p.wsv_b[s][d]; return; }
  idx -= 256;
  if (idx < 256){ p.b1_f[idx] = p.b1[idx]; return; }
  idx -= 256;
  if (idx < 64){ p.b2_f[idx] = p.b2[idx]; return; }
  idx -= 64;
  if (idx < 256){ p.lng_f[idx] = p.lng[idx]; return; }
  idx -= 256;
  if (idx < 256){ p.lnb_f[idx] = p.lnb[idx]; return; }
  idx -= 256;
  if (idx < 256){ p.gb_f[idx] = p.gbias[idx]; return; }
}

// ---------------- MFMA building blocks (16 nodes / block, 4 waves) ----------
__device__ __forceinline__ void mfma_vh_vn(const u16* whPs, const u16* xvb, u16* vhb2,
                                           u16* xsb, int lane, int wave, int tid){
  fx4 a0={0,0,0,0}, a1={0,0,0,0}, a2={0,0,0,0};
  #pragma unroll
  for (int ks=0; ks<2; ks++){
    bs8 b = glb8(whPs + (ks*4+wave)*512 + lane*8);
    bs8 x0 = lds8(xvb + ( 0 + (lane&15))*XVB_P + ks*32 + ((lane>>4)*8));
    bs8 x1 = lds8(xvb + (16 + (lane&15))*XVB_P + ks*32 + ((lane>>4)*8));
    bs8 x2 = lds8(xvb + (32 + (lane&15))*XVB_P + ks*32 + ((lane>>4)*8));
    a0 = MFMA16(x0,b,a0); a1 = MFMA16(x1,b,a1); a2 = MFMA16(x2,b,a2);
  }
  int h = wave*16 + (lane&15);
  int mrow = (lane>>4)*4;
  #pragma unroll
  for (int r=0;r<4;r++){
    vhb2[( 0+mrow+r)*XVB_P + h] = f2b(a0[r]);
    vhb2[(16+mrow+r)*XVB_P + h] = f2b(a1[r]);
    vhb2[(32+mrow+r)*XVB_P + h] = f2b(a2[r]);
  }
  __syncthreads();
  for (int i=tid; i<1024; i+=256){
    int node=i>>6, hh=i&63;
    float a=b2f(vhb2[node*XVB_P+hh]);
    float b=b2f(vhb2[(16+node)*XVB_P+hh]);
    float c=b2f(vhb2[(32+node)*XVB_P+hh]);
    xsb[node*XSB_P + 256 + hh] = f2b(sqrtf(fmaxf(a*a+b*b+c*c, 1e-8f)));
  }
  __syncthreads();
}

template<int KS>
__device__ __forceinline__ void mfma_sgemm(const u16* wsPs, const float* bias,
                                           const u16* xsb, int lane, int wave, fx4 acc[4]){
  #pragma unroll
  for (int t=0;t<4;t++) acc[t] = (fx4){0.f,0.f,0.f,0.f};
  const u16* arow = xsb + (lane&15)*XSB_P + ((lane>>4)*8);
  #pragma unroll
  for (int ks=0; ks<KS; ks++){
    bs8 a = lds8(arow + ks*32);
    #pragma unroll
    for (int t=0;t<4;t++){
      bs8 b = glb8(wsPs + (ks*16 + wave*4 + t)*512 + lane*8);
      acc[t] = MFMA16(a,b,acc[t]);
    }
  }
  #pragma unroll
  for (int t=0;t<4;t++){
    float bv = bias[(wave*4+t)*16 + (lane&15)];
    acc[t][0]+=bv; acc[t][1]+=bv; acc[t][2]+=bv; acc[t][3]+=bv;
  }
}

__device__ __forceinline__ fx4 mfma_g64(const u16* bP, const u16* sgb, int lane, int wave){
  fx4 acc = {0.f,0.f,0.f,0.f};
  const u16* arow = sgb + (lane&15)*SGB_P + ((lane>>4)*8);
  #pragma unroll
  for (int ks=0; ks<8; ks++){
    bs8 a = lds8(arow + ks*32);
    bs8 b = glb8(bP + (ks*4 + wave)*512 + lane*8);
    acc = MFMA16(a,b,acc);
  }
  return acc;
}

__device__ __forceinline__ void mfma_wv(const u16* wvPs, const u16* vhb2,
                                        int lane, int wave, fx4 vo[3]){
  vo[0]=(fx4){0.f,0.f,0.f,0.f}; vo[1]=vo[0]; vo[2]=vo[0];
  #pragma unroll
  for (int ks=0; ks<2; ks++){
    bs8 b = glb8(wvPs + (ks*4+wave)*512 + lane*8);
    #pragma unroll
    for (int c=0;c<3;c++){
      bs8 a = lds8(vhb2 + (c*16 + (lane&15))*XVB_P + ks*32 + ((lane>>4)*8));
      vo[c] = MFMA16(a,b,vo[c]);
    }
  }
}

// ---------------- k1: q/k/v/g GVPs + comp path (16 nodes / block) -----------
__global__ __launch_bounds__(256) void k1(GP p){
  __shared__ __align__(16) u16 xsb[16*XSB_P];
  __shared__ __align__(16) u16 xvb[48*XVB_P];
  __shared__ __align__(16) u16 vhb2[48*XVB_P];
  __shared__ __align__(16) u16 sgb[16*SGB_P];
  __shared__ float red[8][16];
  __shared__ float lnp[2][16];
  __shared__ float ubuf[16*UBUF_P];
  const int tid = threadIdx.x, lane = tid&63, wave = tid>>6;
  const int n0 = blockIdx.x * 16;

  for (int i=tid;i<1024;i+=256){
    int node=i>>6, c4=(i&63)*4;
    float4 v = *reinterpret_cast<const float4*>(p.x_s + (size_t)(n0+node)*256 + c4);
    u16* d = xsb + node*XSB_P + c4;
    d[0]=f2b(v.x); d[1]=f2b(v.y); d[2]=f2b(v.z); d[3]=f2b(v.w);
  }
  for (int i=tid;i<3072;i+=256){
    int row=i>>6, d=i&63, c=row>>4, node=row&15;
    xvb[row*XVB_P+d] = f2b(p.x_v[(size_t)(n0+node)*192 + d*3 + c]);
  }
  __syncthreads();

  fx4 acc[4];
  #pragma unroll 1
  for (int s=0; s<3; ++s){      // 0=q 1=k 2=v
    mfma_vh_vn(p.whP + s*4096, xvb, vhb2, xsb, lane, wave, tid);
    mfma_sgemm<10>(p.wsP + (size_t)s*81920, p.wsb_f + s*256, xsb, lane, wave, acc);
    u16* KVs = (s==1) ? p.Ks : p.Vs;
    #pragma unroll
    for (int t=0;t<4;t++){
      int ncol=(wave*4+t)*16+(lane&15);
      #pragma unroll
      for (int r=0;r<4;r++){
        int node=((lane>>4)*4)+r;
        float v=acc[t][r];
        float sl=siluf(v);
        if (s==0) p.Qs[(size_t)(n0+node)*256+ncol]=sl;
        else      KVs[(size_t)(n0+node)*256+ncol]=f2b(sl);
        sgb[node*SGB_P+ncol]=f2b(sigm(v));
      }
    }
    __syncthreads();
    fx4 g = mfma_g64(p.wsvP + s*16384, sgb, lane, wave);
    fx4 vo[3];
    mfma_wv(p.wvP + s*4096, vhb2, lane, wave, vo);
    int dout = wave*16+(lane&15);
    #pragma unroll
    for (int r=0;r<4;r++){
      int node=((lane>>4)*4)+r;
      float gg = sigm(g[r] + p.wsvb_f[s*64+dout]);
      if (s==0){
        #pragma unroll
        for (int c=0;c<3;c++)
          p.Qv[(size_t)(n0+node)*192 + c*64 + dout] = vo[c][r]*gg;
      } else {
        u16* KVv=(s==1)?p.Kv:p.Vv;
        #pragma unroll
        for (int c=0;c<3;c++)
          KVv[(size_t)(n0+node)*192 + c*64 + dout] = f2b(vo[c][r]*gg);
      }
    }
    __syncthreads();
  }

  // gate set
  mfma_vh_vn(p.whP + 3*4096, xvb, vhb2, xsb, lane, wave, tid);
  mfma_sgemm<10>(p.wsP + (size_t)3*81920, p.wsb_f + 3*256, xsb, lane, wave, acc);
  {
    float psum[4] = {0.f,0.f,0.f,0.f};
    #pragma unroll
    for (int t=0;t<4;t++){
      int ncol=(wave*4+t)*16+(lane&15);
      float gb = p.gb_f[ncol];
      #pragma unroll
      for (int r=0;r<4;r++){
        int node=((lane>>4)*4)+r;
        float gs = sigm(acc[t][r] + gb);
        p.Gs[(size_t)(n0+node)*256+ncol] = f2b(gs);
        psum[r] += gs;
      }
    }
    #pragma unroll
    for (int r=0;r<4;r++){
      #pragma unroll
      for (int o=1;o<16;o<<=1) psum[r] += __shfl_xor(psum[r], o);
    }
    if ((lane&15)==0){
      #pragma unroll
      for (int r=0;r<4;r++) red[wave][((lane>>4)*4)+r] = psum[r];
    }
    __syncthreads();
    if (tid<16)
      p.Gv[n0+tid] = sigm((red[0][tid]+red[1][tid]+red[2][tid]+red[3][tid])*(1.f/256.f));
    __syncthreads();
  }

  // comp path
  mfma_sgemm<8>(p.w1P, p.b1_f, xsb, lane, wave, acc);
  {
    float s1[4]={0.f,0.f,0.f,0.f}, s2[4]={0.f,0.f,0.f,0.f};
    #pragma unroll
    for (int t=0;t<4;t++)
      #pragma unroll
      for (int r=0;r<4;r++){ float v=acc[t][r]; s1[r]+=v; s2[r]+=v*v; }
    #pragma unroll
    for (int r=0;r<4;r++){
      #pragma unroll
      for (int o=1;o<16;o<<=1){ s1[r]+=__shfl_xor(s1[r],o); s2[r]+=__shfl_xor(s2[r],o); }
    }
    if ((lane&15)==0){
      #pragma unroll
      for (int r=0;r<4;r++){
        red[wave][((lane>>4)*4)+r]=s1[r];
        red[4+wave][((lane>>4)*4)+r]=s2[r];
      }
    }
    __syncthreads();
    if (tid<16){
      float S1=red[0][tid]+red[1][tid]+red[2][tid]+red[3][tid];
      float S2=red[4][tid]+red[5][tid]+red[6][tid]+red[7][tid];
      float mu=S1*(1.f/256.f), var=S2*(1.f/256.f)-mu*mu;
      lnp[0][tid]=mu; lnp[1][tid]=rsqrtf(var+1e-5f);
    }
    __syncthreads();
    #pragma unroll
    for (int t=0;t<4;t++){
      int ncol=(wave*4+t)*16+(lane&15);
      float g=p.lng_f[ncol], b=p.lnb_f[ncol];
      #pragma unroll
      for (int r=0;r<4;r++){
        int node=((lane>>4)*4)+r;
        float h=(acc[t][r]-lnp[0][node])*lnp[1][node]*g + b;
        sgb[node*SGB_P+ncol]=f2b(siluf(h));
      }
    }
    __syncthreads();
    fx4 u = mfma_g64(p.w2P, sgb, lane, wave);
    int rcol = wave*16+(lane&15);
    float b2v = p.b2_f[rcol];
    #pragma unroll
    for (int r=0;r<4;r++)
      ubuf[(((lane>>4)*4)+r)*UBUF_P + rcol] = u[r] + b2v;
    __syncthreads();
    #pragma unroll
    for (int i=0;i<4;i++){
      int node = wave*4+i;
      float uu = ubuf[node*UBUF_P + lane];
      float m = wmax(uu);
      float e = __expf(uu-m);
      float ss = wsum(e);
      p.Pm[(size_t)(n0+node)*64 + lane] = e/ss;
    }
  }
}

// ---------------- k2: per-batch anchor compression (segmented + atomics) -----
__global__ __launch_bounds__(256) void k2(GP p){
  const int tid = threadIdx.x;
  const int bx = blockIdx.x;
  const int chunk = bx & 63, tile = bx >> 6;    // 64 chunks x 14 feature tiles
  const int n0 = chunk * 1024;
  const u16* src; int sst, soff, fbase; bool isCK;
  if (tile < 4)      { src=p.Ks; sst=256; soff=tile*64;      isCK=true;  fbase=soff;      }
  else if (tile < 7) { src=p.Kv; sst=192; soff=(tile-4)*64;  isCK=true;  fbase=256+soff;  }
  else if (tile < 11){ src=p.Vs; sst=256; soff=(tile-7)*64;  isCK=false; fbase=soff;      }
  else               { src=p.Vv; sst=192; soff=(tile-11)*64; isCK=false; fbase=256+soff;  }
  const int fl = tid&63, rg = tid>>6;
  __shared__ __align__(16) float Pl[1024];
  __shared__ __align__(16) float Fl[1024];
  __shared__ int Bl[16];
  float acc[16];
  #pragma unroll
  for (int j=0;j<16;j++) acc[j]=0.f;
  int curb = p.bidx[n0];

  for (int base=0; base<1024; base+=16){
    __syncthreads();
    for (int idx=tid; idx<1024; idx+=256){
      int nn = idx>>6, f = idx&63;
      Pl[idx] = p.Pm[(size_t)(n0+base+nn)*64 + f];
      Fl[idx] = b2f(src[(size_t)(n0+base+nn)*sst + soff + f]);
    }
    if (tid < 16) Bl[tid] = p.bidx[n0+base+tid];
    __syncthreads();
    for (int nn=0; nn<16; nn++){
      int b = Bl[nn];
      if (b != curb){
        if (isCK){
          int basei = (curb*448 + fbase + fl)*64 + rg*16;
          #pragma unroll
          for (int j=0;j<16;j++){ atomicAdd(&p.CK[basei+j], acc[j]); acc[j]=0.f; }
        } else {
          int rb = curb*64 + rg*16;
          #pragma unroll
          for (int j=0;j<16;j++){ atomicAdd(&p.CV[(rb+j)*448 + fbase + fl], acc[j]); acc[j]=0.f; }
        }
        curb = b;
      }
      float x = Fl[nn*64 + fl];
      float4 p0 = *reinterpret_cast<const float4*>(&Pl[nn*64 + rg*16 + 0]);
      float4 p1 = *reinterpret_cast<const float4*>(&Pl[nn*64 + rg*16 + 4]);
      float4 p2 = *reinterpret_cast<const float4*>(&Pl[nn*64 + rg*16 + 8]);
      float4 p3 = *reinterpret_cast<const float4*>(&Pl[nn*64 + rg*16 + 12]);
      acc[0]+=p0.x*x;  acc[1]+=p0.y*x;  acc[2]+=p0.z*x;  acc[3]+=p0.w*x;
      acc[4]+=p1.x*x;  acc[5]+=p1.y*x;  acc[6]+=p1.z*x;  acc[7]+=p1.w*x;
      acc[8]+=p2.x*x;  acc[9]+=p2.y*x;  acc[10]+=p2.z*x; acc[11]+=p2.w*x;
      acc[12]+=p3.x*x; acc[13]+=p3.y*x; acc[14]+=p3.z*x; acc[15]+=p3.w*x;
    }
  }
  if (isCK){
    int basei = (curb*448 + fbase + fl)*64 + rg*16;
    #pragma unroll
    for (int j=0;j<16;j++) atomicAdd(&p.CK[basei+j], acc[j]);
  } else {
    int rb = curb*64 + rg*16;
    #pragma unroll
    for (int j=0;j<16;j++) atomicAdd(&p.CV[(rb+j)*448 + fbase + fl], acc[j]);
  }
}

// ------------- k2b: pack CK (with SCALE) and CV into bf16 B-fragments --------
// CKP[b][ks14][nt4][lane][8]: B[k=f][n=r];  CVP[b][ks2][nt28][lane][8]: B[k=r][n=f]
__global__ __launch_bounds__(256) void k2b(GP p){
  int idx = blockIdx.x*256 + threadIdx.x;
  if (idx < 229376){
    int b=idx/28672, r=idx%28672;
    int ks=r/2048, r2=r%2048, nt=r2/512, r3=r2%512, ln=r3/8, j=r3&7;
    int f=ks*32+((ln>>4)*8)+j, rr=nt*16+(ln&15);
    p.CKP[idx] = f2b(p.CK[((size_t)b*448+f)*64+rr] * 0.047245559f);
    return;
  }
  idx -= 229376;
  int b=idx/28672, r=idx%28672;
  int ks=r/14336, r2=r%14336, nt=r2/512, r3=r2%512, ln=r3/8, j=r3&7;
  int rr=ks*32+((ln>>4)*8)+j, f=nt*16+(ln&15);
  p.CVP[idx] = f2b(p.CV[((size_t)b*64+rr)*448+f]);
}

// ---------------- k3: MFMA attention + gating + output GVP -------------------
__global__ __launch_bounds__(256) void k3(GP p){
  __shared__ __align__(16) char smem[35072];
  u16* xq   = (u16*)smem;               // phase1: [16][XQ_P]
  u16* atb  = (u16*)(smem+15360);       // phase1: [16][AT_P]
  u16* xsb  = (u16*)(smem+17664);       // [16][XSB_P]
  u16* xvb  = (u16*)(smem+28160);       // [48][XVB_P]
  u16* vhb2 = (u16*)smem;               // phase2 (aliases xq)
  u16* sgb  = (u16*)(smem+6912*2);      // phase2: [16][SGB_P] -- wait, see below
  __shared__ float redm[4][16];
  __shared__ float reds[4][16];
  __shared__ int Bl[16];
  const int tid = threadIdx.x;
  const int n0 = blockIdx.x * 16;
  const int lane = tid & 63, wave = tid >> 6;
  // fix sgb: vhb2 occupies [0,6912); sgb occupies [6912, 6912+8448=15360)
  sgb = (u16*)(smem + 6912);

  // stage Q (concat Qs|Qv) as bf16 A-fragments
  for (int idx=tid; idx<7168; idx+=256){
    int node=idx/448, f=idx-node*448;
    float v = (f<256) ? p.Qs[(size_t)(n0+node)*256+f]
                      : p.Qv[(size_t)(n0+node)*192+(f-256)];
    xq[node*XQ_P+f] = f2b(v);
  }
  if (tid<16) Bl[tid] = p.bidx[n0+tid];
  __syncthreads();

  // ---- attention over the block's distinct batches (usually 1) ----
  int bb = Bl[0];
  while (true){
    // logits: [16 nodes] x [64 anchors], K=448
    fx4 lac = {0.f,0.f,0.f,0.f};
    {
      const u16* ckb = p.CKP + (size_t)bb*28672;
      const u16* arow = xq + (lane&15)*XQ_P + ((lane>>4)*8);
      #pragma unroll
      for (int ks=0; ks<14; ks++){
        bs8 a = lds8(arow + ks*32);
        bs8 b = glb8(ckb + (ks*4+wave)*512 + lane*8);
        lac = MFMA16(a,b,lac);
      }
    }
    // softmax over 64 anchors per node (16-lane + cross-wave reduce)
    float loc[4];
    #pragma unroll
    for (int r=0;r<4;r++){
      float m = lac[r];
      #pragma unroll
      for (int o=1;o<16;o<<=1) m = fmaxf(m, __shfl_xor(m,o));
      loc[r]=m;
    }
    if ((lane&15)==0){
      #pragma unroll
      for (int r=0;r<4;r++) redm[wave][((lane>>4)*4)+r]=loc[r];
    }
    __syncthreads();
    float e4[4];
    #pragma unroll
    for (int r=0;r<4;r++){
      int node=((lane>>4)*4)+r;
      float gm = fmaxf(fmaxf(redm[0][node],redm[1][node]),
                       fmaxf(redm[2][node],redm[3][node]));
      float e = __expf(lac[r]-gm);
      e4[r]=e;
      float s=e;
      #pragma unroll
      for (int o=1;o<16;o<<=1) s += __shfl_xor(s,o);
      loc[r]=s;
    }
    if ((lane&15)==0){
      #pragma unroll
      for (int r=0;r<4;r++) reds[wave][((lane>>4)*4)+r]=loc[r];
    }
    __syncthreads();
    #pragma unroll
    for (int r=0;r<4;r++){
      int node=((lane>>4)*4)+r;
      float tot = reds[0][node]+reds[1][node]+reds[2][node]+reds[3][node];
      atb[node*AT_P + wave*16 + (lane&15)] = f2b(e4[r]/tot);
    }
    __syncthreads();
    // PV: [16 nodes] x [448 features], K=64; wave handles ntiles wave*7..+6
    {
      const u16* cvb = p.CVP + (size_t)bb*28672;
      const u16* prow = atb + (lane&15)*AT_P + ((lane>>4)*8);
      bs8 a0 = lds8(prow);
      bs8 a1 = lds8(prow + 32);
      #pragma unroll
      for (int t=0;t<7;t++){
        int nt = wave*7 + t;
        fx4 pv = {0.f,0.f,0.f,0.f};
        pv = MFMA16(a0, glb8(cvb + nt*512 + lane*8), pv);
        pv = MFMA16(a1, glb8(cvb + (28+nt)*512 + lane*8), pv);
        int f = nt*16 + (lane&15);
        #pragma unroll
        for (int r=0;r<4;r++){
          int node=((lane>>4)*4)+r;
          if (Bl[node]!=bb) continue;
          int n = n0+node;
          if (f < 256){
            float gs = b2f(p.Gs[(size_t)n*256+f]);
            xsb[node*XSB_P+f] = f2b(pv[r]*gs);
          } else {
            int fm=f-256, c=fm>>6, d=fm&63;
            xvb[(c*16+node)*XVB_P+d] = f2b(pv[r]*p.Gv[n]);
          }
        }
      }
    }
    // next distinct batch in block (uniform across threads)
    int nxt = 0x7fffffff;
    #pragma unroll
    for (int i=0;i<16;i++){ int v=Bl[i]; if (v>bb && v<nxt) nxt=v; }
    if (nxt==0x7fffffff) break;
    bb = nxt;
    __syncthreads();   // atb rewrite hazard
  }
  __syncthreads();     // xq dead; phase2 may overwrite (vhb2/sgb alias)

  // output GVP (set 4 for wh/ws, set 3 for wv/wsv)
  mfma_vh_vn(p.whP + 4*4096, xvb, vhb2, xsb, lane, wave, tid);
  fx4 acc[4];
  mfma_sgemm<10>(p.wsP + (size_t)4*81920, p.wsb_f + 4*256, xsb, lane, wave, acc);
  #pragma unroll
  for (int t=0;t<4;t++){
    int ncol=(wave*4+t)*16+(lane&15);
    #pragma unroll
    for (int r=0;r<4;r++){
      int node=((lane>>4)*4)+r;
      float v=acc[t][r];
      p.Qs[(size_t)(n0+node)*256+ncol]=siluf(v);
      sgb[node*SGB_P+ncol]=f2b(sigm(v));
    }
  }
  __syncthreads();
  fx4 g = mfma_g64(p.wsvP + 3*16384, sgb, lane, wave);
  fx4 vo[3];
  mfma_wv(p.wvP + 3*4096, vhb2, lane, wave, vo);
  int dout = wave*16+(lane&15);
  #pragma unroll
  for (int r=0;r<4;r++){
    int node=((lane>>4)*4)+r;
    float gg = sigm(g[r] + p.wsvb_f[3*64+dout]);
    #pragma unroll
    for (int c=0;c<3;c++)
      p.Qv[(size_t)(n0+node)*192 + dout*3 + c] = vo[c][r]*gg;   // [N,DV,3]
  }
}

// ---------------- host ------------------------------------------------------
extern "C" void kernel_launch(void* const* d_in, const int* in_sizes, int n_in,
                              void* d_out, int out_size, void* d_ws, size_t ws_size,
                              hipStream_t stream){
  (void)in_sizes; (void)n_in; (void)out_size; (void)ws_size;
  GP p;
  p.x_s  = (const float*)d_in[0];
  p.x_v  = (const float*)d_in[1];
  p.bidx = (const int*)d_in[2];
  // set order: 0=q 1=k 2=v 3=g 4=o  (wv/wsv: 0=q 1=k 2=v 3=o)
  const int whI[5]  = {3, 9, 15, 33, 21};
  const int wswI[5] = {4, 10, 16, 34, 22};
  const int wsbI[5] = {5, 11, 17, 35, 23};
  const int wvI[4]  = {6, 12, 18, 24};
  const int wsvwI[4]= {7, 13, 19, 25};
  const int wsvbI[4]= {8, 14, 20, 26};
  for (int s=0;s<5;s++){
    p.wh[s]   = (const float*)d_in[whI[s]];
    p.ws_w[s] = (const float*)d_in[wswI[s]];
    p.ws_b[s] = (const float*)d_in[wsbI[s]];
  }
  for (int s=0;s<4;s++){
    p.wv[s]    = (const float*)d_in[wvI[s]];
    p.wsv_w[s] = (const float*)d_in[wsvwI[s]];
    p.wsv_b[s] = (const float*)d_in[wsvbI[s]];
  }
  p.w1    = (const float*)d_in[27];
  p.b1    = (const float*)d_in[28];
  p.lng   = (const float*)d_in[29];
  p.lnb   = (const float*)d_in[30];
  p.w2    = (const float*)d_in[31];
  p.b2    = (const float*)d_in[32];
  p.gbias = (const float*)d_in[36];

  char* w = (char*)d_ws;
  auto alloc = [&](size_t bytes)->char*{
    char* r = w; w += (bytes + 255) & ~(size_t)255; return r;
  };
  p.wsP   = (u16*)alloc(409600u*2);
  p.whP   = (u16*)alloc(20480u*2);
  p.wvP   = (u16*)alloc(16384u*2);
  p.wsvP  = (u16*)alloc(65536u*2);
  p.w1P   = (u16*)alloc(65536u*2);
  p.w2P   = (u16*)alloc(16384u*2);
  p.wsb_f  = (float*)alloc(1280u*4);
  p.wsvb_f = (float*)alloc(256u*4);
  p.b1_f   = (float*)alloc(256u*4);
  p.b2_f   = (float*)alloc(64u*4);
  p.lng_f  = (float*)alloc(256u*4);
  p.lnb_f  = (float*)alloc(256u*4);
  p.gb_f   = (float*)alloc(256u*4);
  p.Ks = (u16*)alloc((size_t)65536*256*2);
  p.Vs = (u16*)alloc((size_t)65536*256*2);
  p.Kv = (u16*)alloc((size_t)65536*192*2);
  p.Vv = (u16*)alloc((size_t)65536*192*2);
  p.Gs = (u16*)alloc((size_t)65536*256*2);
  p.Pm = (float*)alloc((size_t)65536*64*4);
  p.Gv = (float*)alloc((size_t)65536*4);
  p.CK = (float*)alloc((size_t)8*448*64*4);
  p.CV = (float*)alloc((size_t)8*448*64*4);
  p.CKP = (u16*)alloc((size_t)8*448*64*2);
  p.CVP = (u16*)alloc((size_t)8*448*64*2);
  p.Qs = (float*)d_out;
  p.Qv = (float*)d_out + (size_t)65536*256;

  hipMemsetAsync(p.CK, 0, (size_t)8*448*64*4, stream);
  hipMemsetAsync(p.CV, 0, (size_t)8*448*64*4, stream);
  kprep<<<2331, 256, 0, stream>>>(p);
  k1<<<4096, 256, 0, stream>>>(p);
  k2<<<896, 256, 0, stream>>>(p);
  k2b<<<1792, 256, 0, stream>>>(p);
  k3<<<4096, 256, 0, stream>>>(p);
}